// Round 4
// baseline (349.779 us; speedup 1.0000x reference)
//
#include <hip/hip_runtime.h>

// Problem constants
#define BB   4
#define CC   128
#define DHW  32768           // 32*32*32
#define NN   131072          // BB*DHW
#define KK   1024

// Output layout (floats, concatenated in reference return order)
#define OUT_Q    0
#define OUT_LOSS 16777216
#define OUT_IDX  16777217
#define OUT_ESUM 16908289
#define OUT_EMB  16908545

// Workspace layout (float offsets). Total ~2.1 MB.
#define WS_EMBT  0           // 131072 floats: embT[c][k]  (coalesced gather)
#define WS_ENH   131072      // 1024 floats: 0.5*||e_k||^2
#define WS_LOSS  132096      // 1 float loss accumulator
#define WS_CNT   132097      // 1 int rescue counter
#define WS_IDX   132100      // 131072 ints
#define WS_LIST  263172      // 131072 ints rescue list
#define WS_EMBF  394244      // 131072 floats: bf16 hi/lo B-fragments

// Key error budget: 3-pass split-bf16 <= ~0.008 worst; packed-key quantization
// (10 mantissa bits cleared, |key| < 256) <= 0.0156. EPS = 2^-4 covers 2x.
#define EPS_GAP  0.0625f

typedef __attribute__((ext_vector_type(8))) short  short8;   // 8 x bf16
typedef __attribute__((ext_vector_type(4))) float  f32x4;

__device__ inline unsigned short f2bf(float f) {              // RNE fp32->bf16
    unsigned u = __float_as_uint(f);
    return (unsigned short)((u + 0x7FFFu + ((u >> 16) & 1u)) >> 16);
}
__device__ inline float bf2f(unsigned short h) {
    return __uint_as_float(((unsigned)h) << 16);
}
// monotone float -> uint (unsigned compare == float compare)
__device__ inline unsigned fmap(float f) {
    unsigned u = __float_as_uint(f);
    return u ^ (((int)u >> 31) | 0x80000000u);
}
__device__ inline float funmap(unsigned u) {
    unsigned b = (u & 0x80000000u) ? (u ^ 0x80000000u) : ~u;
    return __uint_as_float(b);
}

// ---------------------------------------------------------------------------
// prep (fused): embT transpose, 0.5*||e||^2, B-fragments, zero accumulators.
// ---------------------------------------------------------------------------
__global__ __launch_bounds__(128) void prep_kernel(const float* __restrict__ emb,
                                                   float* __restrict__ embT,
                                                   float* __restrict__ enh,
                                                   short8* __restrict__ embF,
                                                   float* __restrict__ loss_acc,
                                                   int* __restrict__ cnt) {
    const int k = blockIdx.x;     // code 0..1023
    const int c = threadIdx.x;    // 0..127
    __shared__ float row[CC];
    __shared__ float part[2];
    float v = emb[k * CC + c];
    row[c] = v;
    embT[c * KK + k] = v;
    float s = v * v;
    #pragma unroll
    for (int o = 32; o > 0; o >>= 1) s += __shfl_down(s, o);
    if ((c & 63) == 0) part[c >> 6] = s;
    __syncthreads();
    if (c == 0) {
        enh[k] = 0.5f * (part[0] + part[1]);
        if (k == 0) { *loss_acc = 0.0f; *cnt = 0; }
    }
    // B fragments for mfma_f32_16x16x32_bf16: code k -> chunk cc=k>>4, col k&15
    if (c < 32) {
        const int kc = c >> 3, quad = (c >> 1) & 3, p = c & 1;
        const int c0 = kc * 32 + quad * 8;
        short8 f;
        #pragma unroll
        for (int j = 0; j < 8; ++j) {
            float val = row[c0 + j];
            unsigned short hb = f2bf(val);
            f[j] = p ? (short)f2bf(val - bf2f(hb)) : (short)hb;
        }
        embF[(k >> 4) * 512 + (kc * 2 + p) * 64 + quad * 16 + (k & 15)] = f;
    }
}

// ---------------------------------------------------------------------------
// argmin v4: barrier-free. Wave owns 32 vectors (2 M-tiles), A hi/lo frags
// register-resident; B fragments loaded straight from global (L2-resident,
// coalesced 1KB/inst). Best/second-best kept as packed (key|code) uints.
// ---------------------------------------------------------------------------
__global__ __launch_bounds__(256, 4) void argmin_kernel(const float* __restrict__ x,
                                                        const float4* __restrict__ embF4,
                                                        const float* __restrict__ enh,
                                                        int* __restrict__ out_idx,
                                                        int* __restrict__ cnt,
                                                        int* __restrict__ list) {
    const int t    = threadIdx.x;
    const int wave = t >> 6;
    const int lane = t & 63;
    const int quad = lane >> 4;
    const int l15  = lane & 15;

    const int n_wave = blockIdx.x * 128 + wave * 32;
    const int b      = n_wave >> 15;
    const int dhw0   = n_wave & (DHW - 1);
    const float* __restrict__ xb = x + (size_t)b * CC * DHW + dhw0;

    // A fragments: A[m=l15][k=quad*8+j]
    short8 a_hi[2][4], a_lo[2][4];
    #pragma unroll
    for (int tile = 0; tile < 2; ++tile) {
        const int voff = tile * 16 + l15;
        #pragma unroll
        for (int kc = 0; kc < 4; ++kc) {
            const int c0 = kc * 32 + quad * 8;
            #pragma unroll
            for (int j = 0; j < 8; ++j) {
                float v = xb[(size_t)(c0 + j) * DHW + voff];
                unsigned short hb = f2bf(v);
                a_hi[tile][kc][j] = (short)hb;
                a_lo[tile][kc][j] = (short)f2bf(v - bf2f(hb));
            }
        }
    }

    // packed (quantized key | code) best / second-best, per (tile,row)
    unsigned bv1[2][4], bv2[2][4];
    #pragma unroll
    for (int tile = 0; tile < 2; ++tile)
        #pragma unroll
        for (int r = 0; r < 4; ++r) { bv1[tile][r] = 0xFFFFFFFFu; bv2[tile][r] = 0xFFFFFFFFu; }

    const short8* __restrict__ bf = (const short8*)embF4;

    for (int cc = 0; cc < 64; ++cc) {
        f32x4 acc0 = {0.f, 0.f, 0.f, 0.f};
        f32x4 acc1 = {0.f, 0.f, 0.f, 0.f};
        #pragma unroll
        for (int kc = 0; kc < 4; ++kc) {
            const short8 bh = bf[cc * 512 + (kc * 2 + 0) * 64 + lane];
            const short8 bl = bf[cc * 512 + (kc * 2 + 1) * 64 + lane];
            acc0 = __builtin_amdgcn_mfma_f32_16x16x32_bf16(a_hi[0][kc], bh, acc0, 0, 0, 0);
            acc1 = __builtin_amdgcn_mfma_f32_16x16x32_bf16(a_hi[1][kc], bh, acc1, 0, 0, 0);
            acc0 = __builtin_amdgcn_mfma_f32_16x16x32_bf16(a_lo[0][kc], bh, acc0, 0, 0, 0);
            acc1 = __builtin_amdgcn_mfma_f32_16x16x32_bf16(a_lo[1][kc], bh, acc1, 0, 0, 0);
            acc0 = __builtin_amdgcn_mfma_f32_16x16x32_bf16(a_hi[0][kc], bl, acc0, 0, 0, 0);
            acc1 = __builtin_amdgcn_mfma_f32_16x16x32_bf16(a_hi[1][kc], bl, acc1, 0, 0, 0);
        }
        // C/D: col = lane&15 (code), row = quad*4 + reg
        const unsigned code  = cc * 16 + l15;
        const float    enh_v = enh[code];
        #pragma unroll
        for (int r = 0; r < 4; ++r) {
            unsigned p0 = (fmap(enh_v - acc0[r]) & 0xFFFFFC00u) | code;
            unsigned m0 = max(bv1[0][r], p0);
            bv2[0][r] = min(bv2[0][r], m0);
            bv1[0][r] = min(bv1[0][r], p0);
            unsigned p1 = (fmap(enh_v - acc1[r]) & 0xFFFFFC00u) | code;
            unsigned m1 = max(bv1[1][r], p1);
            bv2[1][r] = min(bv2[1][r], m1);
            bv1[1][r] = min(bv1[1][r], p1);
        }
    }

    // reduce across the 16 columns of each quad-row group (xor < 16 keeps quad)
    #pragma unroll
    for (int tile = 0; tile < 2; ++tile) {
        #pragma unroll
        for (int r = 0; r < 4; ++r) {
            unsigned v1 = bv1[tile][r], v2 = bv2[tile][r];
            #pragma unroll
            for (int off = 1; off < 16; off <<= 1) {
                unsigned o1 = (unsigned)__shfl_xor((int)v1, off, 64);
                unsigned o2 = (unsigned)__shfl_xor((int)v2, off, 64);
                v2 = min(min(v2, o2), max(v1, o1));
                v1 = min(v1, o1);
            }
            if (l15 == 0) {
                const int n = n_wave + tile * 16 + quad * 4 + r;
                out_idx[n] = (int)(v1 & 1023u);
                const float f1 = funmap(v1 & 0xFFFFFC00u);
                const float f2 = funmap(v2 & 0xFFFFFC00u);
                if (f2 - f1 < EPS_GAP) {
                    int pos = atomicAdd(cnt, 1);
                    list[pos] = n;
                }
            }
        }
    }
}

// ---------------------------------------------------------------------------
// rescue: exact fp32 argmin for flagged vectors, 8 per block-iteration,
// codebook streamed coalesced via embT.
// ---------------------------------------------------------------------------
__global__ __launch_bounds__(256) void rescue_kernel(const float* __restrict__ x,
                                                     const float* __restrict__ embT,
                                                     const float* __restrict__ enh,
                                                     const int* __restrict__ cnt,
                                                     const int* __restrict__ list,
                                                     int* __restrict__ out_idx) {
    __shared__ float xs[8][CC];
    __shared__ float rv[8][256];
    __shared__ int   ri[8][256];
    __shared__ int   ns[8];
    const int t = threadIdx.x;
    const int m = *cnt;
    for (int base = blockIdx.x * 8; base < m; base += gridDim.x * 8) {
        const int m8 = min(8, m - base);
        if (t < 8) ns[t] = (t < m8) ? list[base + t] : 0;
        __syncthreads();
        for (int i = t; i < 8 * CC; i += 256) {
            const int vec = i >> 7, c = i & 127;
            if (vec < m8) {
                const int n = ns[vec], bb = n >> 15, dhw = n & (DHW - 1);
                xs[vec][c] = x[(size_t)bb * CC * DHW + (size_t)c * DHW + dhw];
            }
        }
        __syncthreads();
        float bvv[8]; int bii[8];
        #pragma unroll
        for (int v = 0; v < 8; ++v) { bvv[v] = 1e30f; bii[v] = 0; }
        for (int kb = 0; kb < 4; ++kb) {
            const int k = kb * 256 + t;
            float acc[8];
            #pragma unroll
            for (int v = 0; v < 8; ++v) acc[v] = 0.0f;
            for (int c = 0; c < CC; ++c) {
                const float ev = embT[c * KK + k];   // coalesced across threads
                #pragma unroll
                for (int v = 0; v < 8; ++v) acc[v] = fmaf(xs[v][c], ev, acc[v]);
            }
            const float eh = enh[k];
            #pragma unroll
            for (int v = 0; v < 8; ++v) {
                const float key = eh - acc[v];
                if (key < bvv[v] || (key == bvv[v] && k < bii[v])) { bvv[v] = key; bii[v] = k; }
            }
        }
        #pragma unroll
        for (int v = 0; v < 8; ++v) { rv[v][t] = bvv[v]; ri[v][t] = bii[v]; }
        __syncthreads();
        for (int s = 128; s >= 1; s >>= 1) {
            if (t < s) {
                #pragma unroll
                for (int v = 0; v < 8; ++v) {
                    const float ov = rv[v][t + s]; const int oi = ri[v][t + s];
                    if (ov < rv[v][t] || (ov == rv[v][t] && oi < ri[v][t])) {
                        rv[v][t] = ov; ri[v][t] = oi;
                    }
                }
            }
            __syncthreads();
        }
        if (t < m8) out_idx[ns[t]] = ri[t][0];
        __syncthreads();
    }
}

// ---------------------------------------------------------------------------
// quant: gather codes, write straight-through output, accumulate loss sum.
// ---------------------------------------------------------------------------
__global__ __launch_bounds__(256) void quant_kernel(const float* __restrict__ x,
                                                    const float* __restrict__ embT,
                                                    const int* __restrict__ idx,
                                                    float* __restrict__ out,
                                                    float* __restrict__ loss_acc) {
    const int bid   = blockIdx.x;           // 0..511
    const int c0    = (bid & 3) * 32;
    const int chunk = bid >> 2;             // 0..127
    const int b     = chunk >> 5;           // 0..3
    const int dhw   = (chunk & 31) * 1024 + threadIdx.x * 4;
    const int n     = b * DHW + dhw;
    const int4 kk   = *(const int4*)(idx + n);
    const size_t base = (size_t)b * CC * DHW + dhw;

    float lacc = 0.0f;
    for (int c = c0; c < c0 + 32; ++c) {
        const float4 in4 = *(const float4*)(x + base + (size_t)c * DHW);
        const float* er  = embT + c * KK;
        const float d0 = er[kk.x] - in4.x;
        const float d1 = er[kk.y] - in4.y;
        const float d2 = er[kk.z] - in4.z;
        const float d3 = er[kk.w] - in4.w;
        float4 o4;
        o4.x = in4.x + d0; o4.y = in4.y + d1;
        o4.z = in4.z + d2; o4.w = in4.w + d3;
        *(float4*)(out + base + (size_t)c * DHW) = o4;
        lacc += d0 * d0 + d1 * d1 + d2 * d2 + d3 * d3;
    }
    #pragma unroll
    for (int o = 32; o > 0; o >>= 1) lacc += __shfl_down(lacc, o);
    __shared__ float part[4];
    if ((threadIdx.x & 63) == 0) part[threadIdx.x >> 6] = lacc;
    __syncthreads();
    if (threadIdx.x == 0)
        atomicAdd(loss_acc, part[0] + part[1] + part[2] + part[3]);
}

// ---------------------------------------------------------------------------
// tail: indices as float, embedding copy, encodings_sum zeros, loss finalize
// ---------------------------------------------------------------------------
__global__ __launch_bounds__(256) void tail_kernel(const int* __restrict__ idx,
                                                   const float* __restrict__ emb,
                                                   const float* __restrict__ loss_acc,
                                                   float* __restrict__ out) {
    const int g = blockIdx.x * 256 + threadIdx.x;
    if (g < NN) {
        out[OUT_IDX + g] = (float)idx[g];
    } else if (g < 2 * NN) {
        out[OUT_EMB + (g - NN)] = emb[g - NN];
    } else if (g < 2 * NN + 256) {
        out[OUT_ESUM + (g - 2 * NN)] = 0.0f;
    } else if (g == 2 * NN + 256) {
        out[OUT_LOSS] = 2.5f * (*loss_acc) / 16777216.0f;
    }
}

extern "C" void kernel_launch(void* const* d_in, const int* in_sizes, int n_in,
                              void* d_out, int out_size, void* d_ws, size_t ws_size,
                              hipStream_t stream) {
    const float* x   = (const float*)d_in[0];   // [4,128,32,32,32] fp32
    const float* emb = (const float*)d_in[1];   // [1024,128] fp32
    float* out = (float*)d_out;
    float* ws  = (float*)d_ws;

    float*  embT     = ws + WS_EMBT;
    float*  enh      = ws + WS_ENH;
    float*  loss_acc = ws + WS_LOSS;
    int*    cnt      = (int*)(ws + WS_CNT);
    int*    idx      = (int*)(ws + WS_IDX);
    int*    list     = (int*)(ws + WS_LIST);
    float*  embF     = ws + WS_EMBF;

    prep_kernel<<<KK, 128, 0, stream>>>(emb, embT, enh, (short8*)embF, loss_acc, cnt);
    argmin_kernel<<<NN / 128, 256, 0, stream>>>(x, (const float4*)embF, enh, idx, cnt, list);
    rescue_kernel<<<256, 256, 0, stream>>>(x, embT, enh, cnt, list, idx);
    quant_kernel<<<512, 256, 0, stream>>>(x, embT, idx, out, loss_acc);
    tail_kernel<<<(2 * NN + 256 + 256) / 256 + 1, 256, 0, stream>>>(idx, emb, loss_acc, out);
}